// Round 18
// baseline (114.280 us; speedup 1.0000x reference)
//
#include <hip/hip_runtime.h>
#include <hip/hip_bf16.h>
#include <math.h>

// Fused LSTM via bf16 MFMA. B=16384, T=28, F=28(pad 32, feat28=bias), H=128.
// Round 18 = round-17 MINUS the s_setprio toggles. The 4 toggles/step acted
// as scheduling fences pinning gate-VALU outside the MFMA regions (m141-type
// order-pinning; m190: setprio hurts lockstep structures). Single-variable
// change; hot-loop semantics bit-identical (absmax tripwire 0.001953125).
constexpr int LH = 128;
constexpr int LG = 512;
constexpr int LT = 28;
constexpr int LF = 28;
constexpr int NS = 32;    // samples per block (two MFMA row-tiles)
constexpr int NTH = 512;  // 8 waves
constexpr int NREC = 8 * 4 * 5;   // (wave, gate-ti, kk) records; kk=4 is W+b

typedef short bf16x8 __attribute__((ext_vector_type(8)));
typedef float f32x4  __attribute__((ext_vector_type(4)));

__device__ __forceinline__ unsigned short rne_bf16(float f) {   // cold path
    unsigned u = __builtin_bit_cast(unsigned, f);
    u += 0x7FFFu + ((u >> 16) & 1u);
    return (unsigned short)(u >> 16);
}
__device__ __forceinline__ unsigned short hw_bf16(float f) {    // hot path
    __hip_bfloat16 h = __float2bfloat16(f);
    return __builtin_bit_cast(unsigned short, h);
}
__device__ __forceinline__ float bf16_to_f(unsigned short v) {
    return __builtin_bit_cast(float, (unsigned)v << 16);
}
__device__ __forceinline__ float fsigmoid(float v) {
    return __builtin_amdgcn_rcpf(1.0f + __expf(-v));
}

// h_sh swizzle: row stride = 128 bf16 = 16 granules of 16B. Raw granule g is
// stored at slot g ^ (row & 15) -> frag reads are <=2-way (free).
__device__ __forceinline__ int h_idx(int row, int g, int w2) {  // ushort index
    return row * LH + (((g ^ (row & 15)) << 3) + w2);
}

// ---- K1: pack U/W/b into fragment-ordered bf16 records in d_ws ----
// Record rec = (w*4+ti)*5+kk. Lane l=(quad,r16) holds 8 bf16:
//   kk<4 : U[kk*32+quad*8+e][128*ti+16*w+r16]
//   kk==4: k=quad*8+e -> W[k][col] (k<28), b[col] (k==28), 0 (k>28)
__global__ __launch_bounds__(256) void pack_frags(
    const float* __restrict__ W, const float* __restrict__ U,
    const float* __restrict__ b, unsigned short* __restrict__ ws)
{
    const int gid = blockIdx.x * 256 + threadIdx.x;
    if (gid >= NREC * 64) return;
    const int lane = gid & 63;
    const int rec  = gid >> 6;
    const int kk   = rec % 5;
    const int wti  = rec / 5;
    const int ti   = wti & 3;
    const int w    = wti >> 2;
    const int r16  = lane & 15;
    const int quad = lane >> 4;
    const int col  = 128 * ti + 16 * w + r16;

    unsigned short v[8];
#pragma unroll
    for (int e = 0; e < 8; ++e) {
        float f;
        if (kk < 4) {
            f = U[(kk * 32 + quad * 8 + e) * LG + col];
        } else {
            const int k = quad * 8 + e;
            f = (k < LF) ? W[k * LG + col] : (k == LF ? b[col] : 0.0f);
        }
        v[e] = rne_bf16(f);
    }
    unsigned short* dst = ws + (size_t)gid * 8;
#pragma unroll
    for (int e = 0; e < 8; ++e) dst[e] = v[e];
}

// ---- K2: main fused LSTM ----
__global__ __launch_bounds__(NTH, 4) void lstm_mfma(
    const float* __restrict__ x,          // [B, T, F]
    const bf16x8* __restrict__ frag,      // packed U/W records (d_ws)
    const float* __restrict__ Wd,         // [H, 10]
    const float* __restrict__ bd,         // [10]
    float* __restrict__ out)              // [B, 10]
{
    __shared__ unsigned short xfrag[LT][2][4][16][8];   // 57344 B
    __shared__ unsigned short h_sh[2][NS * LH];         // 16384 B
    __shared__ float wd_lds[LH][10];                    // 5120 B
    __shared__ float logit_lds[NS][10];                 // 1280 B

    const int tid  = threadIdx.x;
    const int wave = tid >> 6;     // 0..7
    const int lane = tid & 63;
    const int r16  = lane & 15;
    const int quad = lane >> 4;
    const long s0  = (long)blockIdx.x * NS;

    // ---- stage x as bf16 fragments, GRANULE-WISE (float4 loads, b128 store)
    {
        constexpr int NGR = LT * 2 * 4 * 16;   // 3584 granules, 7 per thread
#pragma unroll
        for (int g = tid; g < NGR; g += NTH) {
            const int t   = g >> 7;
            const int rem = g & 127;
            const int rt  = rem >> 6;
            const int q   = (rem >> 4) & 3;
            const int r   = rem & 15;
            const float* src = x + (s0 + rt * 16 + r) * (LT * LF) + t * LF + q * 8;
            unsigned short v[8];
            if (q < 3) {
                const float4 a = *(const float4*)(src);
                const float4 c = *(const float4*)(src + 4);
                v[0] = hw_bf16(a.x); v[1] = hw_bf16(a.y);
                v[2] = hw_bf16(a.z); v[3] = hw_bf16(a.w);
                v[4] = hw_bf16(c.x); v[5] = hw_bf16(c.y);
                v[6] = hw_bf16(c.z); v[7] = hw_bf16(c.w);
            } else {
                const float4 a = *(const float4*)(src);   // f24..27
                v[0] = hw_bf16(a.x); v[1] = hw_bf16(a.y);
                v[2] = hw_bf16(a.z); v[3] = hw_bf16(a.w);
                v[4] = 0x3F80;   // bf16(1.0) bias row
                v[5] = 0; v[6] = 0; v[7] = 0;
            }
            *reinterpret_cast<bf16x8*>(&xfrag[t][rt][q][r][0]) =
                *reinterpret_cast<const bf16x8*>(v);
        }
    }

    // ---- stage Wd for the epilogue (covered by the first step barrier) ----
    for (int i = tid; i < LH * 10; i += NTH)
        (&wd_lds[0][0])[i] = Wd[i];

    // ---- startup: Uf via 16 coalesced 16B loads (fragment-ordered) ----
    bf16x8 Uf[4][4];   // [gate ti][kstep kk] -> unified-file AGPRs
#pragma unroll
    for (int ti = 0; ti < 4; ++ti)
#pragma unroll
        for (int kk = 0; kk < 4; ++kk)
            Uf[ti][kk] = frag[((wave * 4 + ti) * 5 + kk) * 64 + lane];

    // per-wave pointers to the 4 W records (kk=4), read fresh each step
    const bf16x8* wrec0 = &frag[((wave * 4 + 0) * 5 + 4) * 64 + lane];
    const bf16x8* wrec1 = &frag[((wave * 4 + 1) * 5 + 4) * 64 + lane];
    const bf16x8* wrec2 = &frag[((wave * 4 + 2) * 5 + 4) * 64 + lane];
    const bf16x8* wrec3 = &frag[((wave * 4 + 3) * 5 + 4) * 64 + lane];

    // zero initial hidden state
    for (int i = tid; i < NS * LH; i += NTH) h_sh[0][i] = 0;

    float cre[2][4];   // cell state: [row-tile][e], s = rt*16 + quad*4 + e
#pragma unroll
    for (int rt = 0; rt < 2; ++rt)
#pragma unroll
        for (int e = 0; e < 4; ++e) cre[rt][e] = 0.0f;

    const f32x4 Z4 = f32x4{0.0f, 0.0f, 0.0f, 0.0f};
    const int gW = 2 * wave + (r16 >> 3);   // raw write granule
    const int w2 = r16 & 7;

    // One LSTM step, compile-time CUR. Row-tiles sequential, one acc[4] live.
    // NO setprio fences: let the scheduler interleave rt1's MFMAs under
    // rt0's gate VALU.
#define LSTM_STEP(T_IDX, CUR)                                                  \
    do {                                                                       \
        __syncthreads();                                                       \
        const bf16x8 wf0 = *wrec0;                                             \
        const bf16x8 wf1 = *wrec1;                                             \
        const bf16x8 wf2 = *wrec2;                                             \
        const bf16x8 wf3 = *wrec3;                                             \
        _Pragma("unroll")                                                      \
        for (int rt = 0; rt < 2; ++rt) {                                       \
            f32x4 a0, a1, a2, a3;                                              \
            {   /* kk = 0 seeds with literal-zero C */                         \
                const bf16x8 h0 = *reinterpret_cast<const bf16x8*>(            \
                    &h_sh[CUR][h_idx(rt * 16 + r16, quad, 0)]);                \
                a0 = __builtin_amdgcn_mfma_f32_16x16x32_bf16(h0, Uf[0][0], Z4, 0, 0, 0); \
                a1 = __builtin_amdgcn_mfma_f32_16x16x32_bf16(h0, Uf[1][0], Z4, 0, 0, 0); \
                a2 = __builtin_amdgcn_mfma_f32_16x16x32_bf16(h0, Uf[2][0], Z4, 0, 0, 0); \
                a3 = __builtin_amdgcn_mfma_f32_16x16x32_bf16(h0, Uf[3][0], Z4, 0, 0, 0); \
            }                                                                  \
            _Pragma("unroll")                                                  \
            for (int kk = 1; kk < 4; ++kk) {                                   \
                const bf16x8 h0 = *reinterpret_cast<const bf16x8*>(            \
                    &h_sh[CUR][h_idx(rt * 16 + r16, kk * 4 + quad, 0)]);       \
                a0 = __builtin_amdgcn_mfma_f32_16x16x32_bf16(h0, Uf[0][kk], a0, 0, 0, 0); \
                a1 = __builtin_amdgcn_mfma_f32_16x16x32_bf16(h0, Uf[1][kk], a1, 0, 0, 0); \
                a2 = __builtin_amdgcn_mfma_f32_16x16x32_bf16(h0, Uf[2][kk], a2, 0, 0, 0); \
                a3 = __builtin_amdgcn_mfma_f32_16x16x32_bf16(h0, Uf[3][kk], a3, 0, 0, 0); \
            }                                                                  \
            {   /* x@W (+bias) last: wf L2-latency hidden under h-chain */     \
                const bf16x8 xa = *reinterpret_cast<const bf16x8*>(            \
                    &xfrag[T_IDX][rt][quad][r16][0]);                          \
                a0 = __builtin_amdgcn_mfma_f32_16x16x32_bf16(xa, wf0, a0, 0, 0, 0); \
                a1 = __builtin_amdgcn_mfma_f32_16x16x32_bf16(xa, wf1, a1, 0, 0, 0); \
                a2 = __builtin_amdgcn_mfma_f32_16x16x32_bf16(xa, wf2, a2, 0, 0, 0); \
                a3 = __builtin_amdgcn_mfma_f32_16x16x32_bf16(xa, wf3, a3, 0, 0, 0); \
            }                                                                  \
            _Pragma("unroll")                                                  \
            for (int e = 0; e < 4; ++e) {                                      \
                const float ig = fsigmoid(a0[e]);                              \
                const float fg = fsigmoid(a1[e]);                              \
                const float gg = fmaxf(a2[e], 0.0f);                           \
                const float og = fsigmoid(a3[e]);                              \
                const float cn = fg * cre[rt][e] + ig * gg;                    \
                cre[rt][e] = cn;                                               \
                const float hv = og * fmaxf(cn, 0.0f);                         \
                h_sh[(CUR) ^ 1][h_idx(rt * 16 + quad * 4 + e, gW, w2)] =       \
                    hw_bf16(hv);                                               \
            }                                                                  \
        }                                                                      \
    } while (0)

#pragma unroll 1
    for (int t = 0; t < LT; t += 2) {
        LSTM_STEP(t, 0);
        LSTM_STEP(t + 1, 1);
    }
#undef LSTM_STEP

    __syncthreads();  // final h (bf16) in h_sh[0]  (LT even)

    // ---- logits: h_final @ Wd + bd (NS*10 = 320 pairs <= 512 threads) ----
    if (tid < NS * 10) {
        const int s   = tid / 10;
        const int cls = tid - s * 10;
        float a = bd[cls];
        for (int k = 0; k < LH; ++k) {
            const float hv = bf16_to_f(
                h_sh[0][s * LH + ((((k >> 3) ^ (s & 15)) << 3) + (k & 7))]);
            a += hv * wd_lds[k][cls];
        }
        logit_lds[s][cls] = a;
    }
    __syncthreads();

    // ---- softmax over 10 classes ----
    if (tid < NS) {
        const int s = tid;
        float m = logit_lds[s][0];
#pragma unroll
        for (int q = 1; q < 10; ++q) m = fmaxf(m, logit_lds[s][q]);
        float e[10], sum = 0.0f;
#pragma unroll
        for (int q = 0; q < 10; ++q) {
            e[q] = expf(logit_lds[s][q] - m);
            sum += e[q];
        }
        const float inv = __builtin_amdgcn_rcpf(sum);
#pragma unroll
        for (int q = 0; q < 10; ++q)
            out[(s0 + s) * 10 + q] = e[q] * inv;
    }
}

extern "C" void kernel_launch(void* const* d_in, const int* in_sizes, int n_in,
                              void* d_out, int out_size, void* d_ws, size_t ws_size,
                              hipStream_t stream) {
    const float* x  = (const float*)d_in[0];
    const float* W  = (const float*)d_in[1];
    const float* U  = (const float*)d_in[2];
    const float* b  = (const float*)d_in[3];
    const float* Wd = (const float*)d_in[4];
    const float* bd = (const float*)d_in[5];
    float* out = (float*)d_out;

    const int B = in_sizes[0] / (LT * LF);   // 16384
    const int blocks = B / NS;               // 512 = 2 per CU, ONE generation

    pack_frags<<<(NREC * 64 + 255) / 256, 256, 0, stream>>>(
        W, U, b, (unsigned short*)d_ws);
    lstm_mfma<<<blocks, NTH, 0, stream>>>(
        x, (const bf16x8*)d_ws, Wd, bd, out);
}

// Round 19
// 87.656 us; speedup vs baseline: 1.3037x; 1.3037x over previous
//
#include <hip/hip_runtime.h>
#include <hip/hip_bf16.h>
#include <math.h>

// Fused LSTM via bf16 MFMA. B=16384, T=28, F=28(pad 32, feat28=bias), H=128.
// Round 19 = EXACT round-17 restore (measured best: 87.8 us). Round-18's
// A/B proved the s_setprio toggles are load-bearing as scheduling-region
// fences: without them the compiler interleaves rt0/rt1 + hoists wf/xa,
// blowing the exactly-full 128-unified-reg budget (64 VGPR + 64 AGPR Uf)
// -> 42 MB scratch spill -> 114 us. Keep the fences.
constexpr int LH = 128;
constexpr int LG = 512;
constexpr int LT = 28;
constexpr int LF = 28;
constexpr int NS = 32;    // samples per block (two MFMA row-tiles)
constexpr int NTH = 512;  // 8 waves
constexpr int NREC = 8 * 4 * 5;   // (wave, gate-ti, kk) records; kk=4 is W+b

typedef short bf16x8 __attribute__((ext_vector_type(8)));
typedef float f32x4  __attribute__((ext_vector_type(4)));

__device__ __forceinline__ unsigned short rne_bf16(float f) {   // cold path
    unsigned u = __builtin_bit_cast(unsigned, f);
    u += 0x7FFFu + ((u >> 16) & 1u);
    return (unsigned short)(u >> 16);
}
__device__ __forceinline__ unsigned short hw_bf16(float f) {    // hot path
    __hip_bfloat16 h = __float2bfloat16(f);
    return __builtin_bit_cast(unsigned short, h);
}
__device__ __forceinline__ float bf16_to_f(unsigned short v) {
    return __builtin_bit_cast(float, (unsigned)v << 16);
}
__device__ __forceinline__ float fsigmoid(float v) {
    return __builtin_amdgcn_rcpf(1.0f + __expf(-v));
}

// h_sh swizzle: row stride = 128 bf16 = 16 granules of 16B. Raw granule g is
// stored at slot g ^ (row & 15) -> frag reads are <=2-way (free).
__device__ __forceinline__ int h_idx(int row, int g, int w2) {  // ushort index
    return row * LH + (((g ^ (row & 15)) << 3) + w2);
}

// ---- K1: pack U/W/b into fragment-ordered bf16 records in d_ws ----
// Record rec = (w*4+ti)*5+kk. Lane l=(quad,r16) holds 8 bf16:
//   kk<4 : U[kk*32+quad*8+e][128*ti+16*w+r16]
//   kk==4: k=quad*8+e -> W[k][col] (k<28), b[col] (k==28), 0 (k>28)
__global__ __launch_bounds__(256) void pack_frags(
    const float* __restrict__ W, const float* __restrict__ U,
    const float* __restrict__ b, unsigned short* __restrict__ ws)
{
    const int gid = blockIdx.x * 256 + threadIdx.x;
    if (gid >= NREC * 64) return;
    const int lane = gid & 63;
    const int rec  = gid >> 6;
    const int kk   = rec % 5;
    const int wti  = rec / 5;
    const int ti   = wti & 3;
    const int w    = wti >> 2;
    const int r16  = lane & 15;
    const int quad = lane >> 4;
    const int col  = 128 * ti + 16 * w + r16;

    unsigned short v[8];
#pragma unroll
    for (int e = 0; e < 8; ++e) {
        float f;
        if (kk < 4) {
            f = U[(kk * 32 + quad * 8 + e) * LG + col];
        } else {
            const int k = quad * 8 + e;
            f = (k < LF) ? W[k * LG + col] : (k == LF ? b[col] : 0.0f);
        }
        v[e] = rne_bf16(f);
    }
    unsigned short* dst = ws + (size_t)gid * 8;
#pragma unroll
    for (int e = 0; e < 8; ++e) dst[e] = v[e];
}

// ---- K2: main fused LSTM ----
__global__ __launch_bounds__(NTH, 4) void lstm_mfma(
    const float* __restrict__ x,          // [B, T, F]
    const bf16x8* __restrict__ frag,      // packed U/W records (d_ws)
    const float* __restrict__ Wd,         // [H, 10]
    const float* __restrict__ bd,         // [10]
    float* __restrict__ out)              // [B, 10]
{
    __shared__ unsigned short xfrag[LT][2][4][16][8];   // 57344 B
    __shared__ unsigned short h_sh[2][NS * LH];         // 16384 B
    __shared__ float wd_lds[LH][10];                    // 5120 B
    __shared__ float logit_lds[NS][10];                 // 1280 B

    const int tid  = threadIdx.x;
    const int wave = tid >> 6;     // 0..7
    const int lane = tid & 63;
    const int r16  = lane & 15;
    const int quad = lane >> 4;
    const long s0  = (long)blockIdx.x * NS;

    // ---- stage x as bf16 fragments, GRANULE-WISE (float4 loads, b128 store)
    {
        constexpr int NGR = LT * 2 * 4 * 16;   // 3584 granules, 7 per thread
#pragma unroll
        for (int g = tid; g < NGR; g += NTH) {
            const int t   = g >> 7;
            const int rem = g & 127;
            const int rt  = rem >> 6;
            const int q   = (rem >> 4) & 3;
            const int r   = rem & 15;
            const float* src = x + (s0 + rt * 16 + r) * (LT * LF) + t * LF + q * 8;
            unsigned short v[8];
            if (q < 3) {
                const float4 a = *(const float4*)(src);
                const float4 c = *(const float4*)(src + 4);
                v[0] = hw_bf16(a.x); v[1] = hw_bf16(a.y);
                v[2] = hw_bf16(a.z); v[3] = hw_bf16(a.w);
                v[4] = hw_bf16(c.x); v[5] = hw_bf16(c.y);
                v[6] = hw_bf16(c.z); v[7] = hw_bf16(c.w);
            } else {
                const float4 a = *(const float4*)(src);   // f24..27
                v[0] = hw_bf16(a.x); v[1] = hw_bf16(a.y);
                v[2] = hw_bf16(a.z); v[3] = hw_bf16(a.w);
                v[4] = 0x3F80;   // bf16(1.0) bias row
                v[5] = 0; v[6] = 0; v[7] = 0;
            }
            *reinterpret_cast<bf16x8*>(&xfrag[t][rt][q][r][0]) =
                *reinterpret_cast<const bf16x8*>(v);
        }
    }

    // ---- stage Wd for the epilogue (covered by the first step barrier) ----
    for (int i = tid; i < LH * 10; i += NTH)
        (&wd_lds[0][0])[i] = Wd[i];

    // ---- startup: Uf via 16 coalesced 16B loads (fragment-ordered) ----
    bf16x8 Uf[4][4];   // [gate ti][kstep kk] -> unified-file AGPRs
#pragma unroll
    for (int ti = 0; ti < 4; ++ti)
#pragma unroll
        for (int kk = 0; kk < 4; ++kk)
            Uf[ti][kk] = frag[((wave * 4 + ti) * 5 + kk) * 64 + lane];

    // per-wave pointers to the 4 W records (kk=4), read fresh each step
    const bf16x8* wrec0 = &frag[((wave * 4 + 0) * 5 + 4) * 64 + lane];
    const bf16x8* wrec1 = &frag[((wave * 4 + 1) * 5 + 4) * 64 + lane];
    const bf16x8* wrec2 = &frag[((wave * 4 + 2) * 5 + 4) * 64 + lane];
    const bf16x8* wrec3 = &frag[((wave * 4 + 3) * 5 + 4) * 64 + lane];

    // zero initial hidden state
    for (int i = tid; i < NS * LH; i += NTH) h_sh[0][i] = 0;

    float cre[2][4];   // cell state: [row-tile][e], s = rt*16 + quad*4 + e
#pragma unroll
    for (int rt = 0; rt < 2; ++rt)
#pragma unroll
        for (int e = 0; e < 4; ++e) cre[rt][e] = 0.0f;

    const f32x4 Z4 = f32x4{0.0f, 0.0f, 0.0f, 0.0f};
    const int gW = 2 * wave + (r16 >> 3);   // raw write granule
    const int w2 = r16 & 7;

    // One LSTM step, compile-time CUR. Row-tiles sequential, one acc[4] live.
    // setprio toggles retained: they bound the scheduler's liveness regions
    // (removing them -> 42 MB spill, round 18).
#define LSTM_STEP(T_IDX, CUR)                                                  \
    do {                                                                       \
        __syncthreads();                                                       \
        const bf16x8 wf0 = *wrec0;                                             \
        const bf16x8 wf1 = *wrec1;                                             \
        const bf16x8 wf2 = *wrec2;                                             \
        const bf16x8 wf3 = *wrec3;                                             \
        _Pragma("unroll")                                                      \
        for (int rt = 0; rt < 2; ++rt) {                                       \
            __builtin_amdgcn_s_setprio(1);                                     \
            f32x4 a0, a1, a2, a3;                                              \
            {   /* kk = 0 seeds with literal-zero C */                         \
                const bf16x8 h0 = *reinterpret_cast<const bf16x8*>(            \
                    &h_sh[CUR][h_idx(rt * 16 + r16, quad, 0)]);                \
                a0 = __builtin_amdgcn_mfma_f32_16x16x32_bf16(h0, Uf[0][0], Z4, 0, 0, 0); \
                a1 = __builtin_amdgcn_mfma_f32_16x16x32_bf16(h0, Uf[1][0], Z4, 0, 0, 0); \
                a2 = __builtin_amdgcn_mfma_f32_16x16x32_bf16(h0, Uf[2][0], Z4, 0, 0, 0); \
                a3 = __builtin_amdgcn_mfma_f32_16x16x32_bf16(h0, Uf[3][0], Z4, 0, 0, 0); \
            }                                                                  \
            _Pragma("unroll")                                                  \
            for (int kk = 1; kk < 4; ++kk) {                                   \
                const bf16x8 h0 = *reinterpret_cast<const bf16x8*>(            \
                    &h_sh[CUR][h_idx(rt * 16 + r16, kk * 4 + quad, 0)]);       \
                a0 = __builtin_amdgcn_mfma_f32_16x16x32_bf16(h0, Uf[0][kk], a0, 0, 0, 0); \
                a1 = __builtin_amdgcn_mfma_f32_16x16x32_bf16(h0, Uf[1][kk], a1, 0, 0, 0); \
                a2 = __builtin_amdgcn_mfma_f32_16x16x32_bf16(h0, Uf[2][kk], a2, 0, 0, 0); \
                a3 = __builtin_amdgcn_mfma_f32_16x16x32_bf16(h0, Uf[3][kk], a3, 0, 0, 0); \
            }                                                                  \
            {   /* x@W (+bias) last: wf L2-latency hidden under h-chain */     \
                const bf16x8 xa = *reinterpret_cast<const bf16x8*>(            \
                    &xfrag[T_IDX][rt][quad][r16][0]);                          \
                a0 = __builtin_amdgcn_mfma_f32_16x16x32_bf16(xa, wf0, a0, 0, 0, 0); \
                a1 = __builtin_amdgcn_mfma_f32_16x16x32_bf16(xa, wf1, a1, 0, 0, 0); \
                a2 = __builtin_amdgcn_mfma_f32_16x16x32_bf16(xa, wf2, a2, 0, 0, 0); \
                a3 = __builtin_amdgcn_mfma_f32_16x16x32_bf16(xa, wf3, a3, 0, 0, 0); \
            }                                                                  \
            __builtin_amdgcn_s_setprio(0);                                     \
            _Pragma("unroll")                                                  \
            for (int e = 0; e < 4; ++e) {                                      \
                const float ig = fsigmoid(a0[e]);                              \
                const float fg = fsigmoid(a1[e]);                              \
                const float gg = fmaxf(a2[e], 0.0f);                           \
                const float og = fsigmoid(a3[e]);                              \
                const float cn = fg * cre[rt][e] + ig * gg;                    \
                cre[rt][e] = cn;                                               \
                const float hv = og * fmaxf(cn, 0.0f);                         \
                h_sh[(CUR) ^ 1][h_idx(rt * 16 + quad * 4 + e, gW, w2)] =       \
                    hw_bf16(hv);                                               \
            }                                                                  \
        }                                                                      \
    } while (0)

#pragma unroll 1
    for (int t = 0; t < LT; t += 2) {
        LSTM_STEP(t, 0);
        LSTM_STEP(t + 1, 1);
    }
#undef LSTM_STEP

    __syncthreads();  // final h (bf16) in h_sh[0]  (LT even)

    // ---- logits: h_final @ Wd + bd (NS*10 = 320 pairs <= 512 threads) ----
    if (tid < NS * 10) {
        const int s   = tid / 10;
        const int cls = tid - s * 10;
        float a = bd[cls];
        for (int k = 0; k < LH; ++k) {
            const float hv = bf16_to_f(
                h_sh[0][s * LH + ((((k >> 3) ^ (s & 15)) << 3) + (k & 7))]);
            a += hv * wd_lds[k][cls];
        }
        logit_lds[s][cls] = a;
    }
    __syncthreads();

    // ---- softmax over 10 classes ----
    if (tid < NS) {
        const int s = tid;
        float m = logit_lds[s][0];
#pragma unroll
        for (int q = 1; q < 10; ++q) m = fmaxf(m, logit_lds[s][q]);
        float e[10], sum = 0.0f;
#pragma unroll
        for (int q = 0; q < 10; ++q) {
            e[q] = expf(logit_lds[s][q] - m);
            sum += e[q];
        }
        const float inv = __builtin_amdgcn_rcpf(sum);
#pragma unroll
        for (int q = 0; q < 10; ++q)
            out[(s0 + s) * 10 + q] = e[q] * inv;
    }
}

extern "C" void kernel_launch(void* const* d_in, const int* in_sizes, int n_in,
                              void* d_out, int out_size, void* d_ws, size_t ws_size,
                              hipStream_t stream) {
    const float* x  = (const float*)d_in[0];
    const float* W  = (const float*)d_in[1];
    const float* U  = (const float*)d_in[2];
    const float* b  = (const float*)d_in[3];
    const float* Wd = (const float*)d_in[4];
    const float* bd = (const float*)d_in[5];
    float* out = (float*)d_out;

    const int B = in_sizes[0] / (LT * LF);   // 16384
    const int blocks = B / NS;               // 512 = 2 per CU, ONE generation

    pack_frags<<<(NREC * 64 + 255) / 256, 256, 0, stream>>>(
        W, U, b, (unsigned short*)d_ws);
    lstm_mfma<<<blocks, NTH, 0, stream>>>(
        x, (const bf16x8*)d_ws, Wd, bd, out);
}